// Round 2
// baseline (2467.284 us; speedup 1.0000x reference)
//
#include <hip/hip_runtime.h>
#include <hip/hip_bf16.h>
#include <math.h>

#define NN 100000
#define NE 800000
#define NG 2048
#define DD 64
#define NR 5

static __device__ __forceinline__ float sigmoidf_(float x) { return 1.0f / (1.0f + expf(-x)); }

// W[r] = sum_b att[r,b] * basis[b]   -> [5,64,64]
__global__ void k_w(const float* __restrict__ att, const float* __restrict__ basis,
                    float* __restrict__ W) {
    int i = blockIdx.x * blockDim.x + threadIdx.x;
    if (i >= NR * DD * DD) return;
    int r = i >> 12;          // /4096
    int de = i & 4095;
    float a = 0.f;
#pragma unroll
    for (int b = 0; b < NR; ++b) a += att[r * NR + b] * basis[b * 4096 + de];
    W[i] = a;
}

// in-degree count (float)
__global__ void k_cnt(const int* __restrict__ dst, float* __restrict__ cnt) {
    int e = blockIdx.x * blockDim.x + threadIdx.x;
    if (e < NE) atomicAdd(&cnt[dst[e]], 1.0f);
}

__global__ void k_inv(float* __restrict__ cnt) {
    int n = blockIdx.x * blockDim.x + threadIdx.x;
    if (n < NN) cnt[n] = 1.0f / fmaxf(cnt[n], 1.0f);
}

// segment starts: seg[g] = lower_bound(batch, g), g in [0, NG]
__global__ void k_seg(const int* __restrict__ batch, int* __restrict__ seg) {
    int g = blockIdx.x * blockDim.x + threadIdx.x;
    if (g > NG) return;
    int lo = 0, hi = NN;
    while (lo < hi) {
        int mid = (lo + hi) >> 1;
        if (batch[mid] < g) lo = mid + 1; else hi = mid;
    }
    seg[g] = lo;
}

// h = relu(x @ lin0_w + lin0_b)
__global__ void k_lin0(const float* __restrict__ x, const float* __restrict__ w,
                       const float* __restrict__ b, float* __restrict__ h) {
    int lane = threadIdx.x & 63, wave = threadIdx.x >> 6;
    float Wc[15];
#pragma unroll
    for (int k = 0; k < 15; ++k) Wc[k] = w[k * DD + lane];
    float bias = b[lane];
    int n0 = blockIdx.x * 256;
    int n1 = min(n0 + 256, NN);
    for (int n = n0 + wave; n < n1; n += 4) {
        int nu = __builtin_amdgcn_readfirstlane(n);
        const float* xr = x + (size_t)nu * 15;
        float a = bias;
#pragma unroll
        for (int k = 0; k < 15; ++k) a += xr[k] * Wc[k];
        h[(size_t)nu * DD + lane] = fmaxf(a, 0.f);
    }
}

// grid.y = r (0..5). r<5: hrel[r] = h @ W[r].  r==5: agg = h @ root  (seeds aggregation).
__global__ void k_transform(const float* __restrict__ h, const float* __restrict__ W5,
                            const float* __restrict__ root, float* __restrict__ hrel,
                            float* __restrict__ agg) {
    int r = blockIdx.y;
    const float* Wm = (r < NR) ? (W5 + (size_t)r * DD * DD) : root;
    float* out = (r < NR) ? (hrel + (size_t)r * NN * DD) : agg;
    int lane = threadIdx.x & 63, wave = threadIdx.x >> 6;
    float Wc[64];
#pragma unroll
    for (int k = 0; k < 64; ++k) Wc[k] = Wm[k * DD + lane];
    int n0 = blockIdx.x * 256;
    int n1 = min(n0 + 256, NN);
    for (int n = n0 + wave; n < n1; n += 4) {
        int nu = __builtin_amdgcn_readfirstlane(n);
        const float4* h4 = (const float4*)(h + (size_t)nu * DD);
        float a0 = 0.f, a1 = 0.f, a2 = 0.f, a3 = 0.f;
#pragma unroll
        for (int k = 0; k < 16; ++k) {
            float4 hv = h4[k];
            a0 += hv.x * Wc[4 * k + 0];
            a1 += hv.y * Wc[4 * k + 1];
            a2 += hv.z * Wc[4 * k + 2];
            a3 += hv.w * Wc[4 * k + 3];
        }
        out[(size_t)nu * DD + lane] = (a0 + a1) + (a2 + a3);
    }
}

// one wave per edge: agg[dst] += inv_cnt[dst] * hrel[et][src]
__global__ void k_scatter(const float* __restrict__ hrel, const int* __restrict__ src,
                          const int* __restrict__ dst, const int* __restrict__ et,
                          const float* __restrict__ invc, float* __restrict__ agg) {
    int gw = (blockIdx.x * blockDim.x + threadIdx.x) >> 6;
    int lane = threadIdx.x & 63;
    if (gw >= NE) return;
    int e = __builtin_amdgcn_readfirstlane(gw);
    int s = src[e], d = dst[e], t = et[e];
    float ic = invc[d];
    float v = hrel[((size_t)t * NN + s) * DD + lane] * ic;
    atomicAdd(agg + (size_t)d * DD + lane, v);
}

// h = relu(agg + conv_b)
__global__ void k_relub(const float* __restrict__ agg, const float* __restrict__ bias,
                        float* __restrict__ h) {
    int i = blockIdx.x * blockDim.x + threadIdx.x;
    if (i >= NN * DD / 4) return;
    float4 v = ((const float4*)agg)[i];
    int cb = (i * 4) & 63;
    v.x = fmaxf(v.x + bias[cb + 0], 0.f);
    v.y = fmaxf(v.y + bias[cb + 1], 0.f);
    v.z = fmaxf(v.z + bias[cb + 2], 0.f);
    v.w = fmaxf(v.w + bias[cb + 3], 0.f);
    ((float4*)h)[i] = v;
}

// LSTM cell: block per graph, 64 threads
__global__ void k_lstm(const float* __restrict__ qstar, float* __restrict__ hx,
                       float* __restrict__ cx, const float* __restrict__ wih,
                       const float* __restrict__ whh, const float* __restrict__ bih,
                       const float* __restrict__ bhh) {
    int g = blockIdx.x;
    int j = threadIdx.x;
    float acc[4];
#pragma unroll
    for (int q = 0; q < 4; ++q) acc[q] = bih[q * DD + j] + bhh[q * DD + j];
    const float4* q4 = (const float4*)(qstar + (size_t)g * 2 * DD);
#pragma unroll 8
    for (int k4 = 0; k4 < 32; ++k4) {
        float4 qv = q4[k4];
#pragma unroll
        for (int q = 0; q < 4; ++q) {
            float4 wv = ((const float4*)(wih + (size_t)(q * DD + j) * 2 * DD))[k4];
            acc[q] += qv.x * wv.x + qv.y * wv.y + qv.z * wv.z + qv.w * wv.w;
        }
    }
    const float4* h4 = (const float4*)(hx + (size_t)g * DD);
#pragma unroll 4
    for (int k4 = 0; k4 < 16; ++k4) {
        float4 hv = h4[k4];
#pragma unroll
        for (int q = 0; q < 4; ++q) {
            float4 wv = ((const float4*)(whh + (size_t)(q * DD + j) * DD))[k4];
            acc[q] += hv.x * wv.x + hv.y * wv.y + hv.z * wv.z + hv.w * wv.w;
        }
    }
    float c_old = cx[(size_t)g * DD + j];
    __syncthreads();  // all hx reads complete before hx writes
    float iv = sigmoidf_(acc[0]);
    float fv = sigmoidf_(acc[1]);
    float gv = tanhf(acc[2]);
    float ov = sigmoidf_(acc[3]);
    float c = fv * c_old + iv * gv;
    cx[(size_t)g * DD + j] = c;
    hx[(size_t)g * DD + j] = ov * tanhf(c);
}

// per-graph segment softmax + weighted sum; writes q_star = [q, r]
__global__ void k_attn(const float* __restrict__ h, const int* __restrict__ seg,
                       const float* __restrict__ hx, float* __restrict__ qstar,
                       float* __restrict__ esc) {
    int g = blockIdx.x;
    int lane = threadIdx.x & 63, wave = threadIdx.x >> 6;
    int s0 = seg[g], s1 = seg[g + 1];
    float q = hx[(size_t)g * DD + lane];
    __shared__ float lmax[4];
    __shared__ float lsum[4];
    __shared__ float lred[4][64];
    float mymax = -INFINITY;
    for (int n = s0 + wave; n < s1; n += 4) {
        float v = h[(size_t)n * DD + lane] * q;
#pragma unroll
        for (int off = 32; off >= 1; off >>= 1) v += __shfl_xor(v, off, 64);
        if (lane == 0) esc[n] = v;
        mymax = fmaxf(mymax, v);
    }
    if (lane == 0) lmax[wave] = mymax;
    __syncthreads();
    float m = fmaxf(fmaxf(lmax[0], lmax[1]), fmaxf(lmax[2], lmax[3]));
    float racc = 0.f, sacc = 0.f;
    for (int n = s0 + wave; n < s1; n += 4) {
        float a = expf(esc[n] - m);
        racc += a * h[(size_t)n * DD + lane];
        sacc += a;
    }
    lred[wave][lane] = racc;
    if (lane == 0) lsum[wave] = sacc;
    __syncthreads();
    if (wave == 0) {
        float r = lred[0][lane] + lred[1][lane] + lred[2][lane] + lred[3][lane];
        float s = lsum[0] + lsum[1] + lsum[2] + lsum[3];
        qstar[(size_t)g * 2 * DD + lane] = q;
        qstar[(size_t)g * 2 * DD + DD + lane] = (s > 0.f) ? (r / s) : 0.f;
    }
}

// out = relu(q_star @ lin1 + b1) @ lin2 + b2
__global__ void k_final(const float* __restrict__ qstar, const float* __restrict__ w1,
                        const float* __restrict__ b1, const float* __restrict__ w2,
                        const float* __restrict__ b2, float* __restrict__ out) {
    int g = blockIdx.x;
    int j = threadIdx.x;  // 64
    float a = b1[j];
    const float* qs = qstar + (size_t)g * 2 * DD;
#pragma unroll 16
    for (int k = 0; k < 2 * DD; ++k) a += qs[k] * w1[k * DD + j];
    float t = fmaxf(a, 0.f);
    __shared__ float ts[64];
    ts[j] = t;
    __syncthreads();
    if (j < 12) {
        float o = b2[j];
#pragma unroll 16
        for (int d = 0; d < DD; ++d) o += ts[d] * w2[d * 12 + j];
        out[(size_t)g * 12 + j] = o;
    }
}

extern "C" void kernel_launch(void* const* d_in, const int* in_sizes, int n_in,
                              void* d_out, int out_size, void* d_ws, size_t ws_size,
                              hipStream_t stream) {
    const float* x     = (const float*)d_in[0];
    const int*   ei    = (const int*)d_in[1];
    const int*   etype = (const int*)d_in[2];
    const int*   batch = (const int*)d_in[3];
    const float* l0w   = (const float*)d_in[4];
    const float* l0b   = (const float*)d_in[5];
    const float* basis = (const float*)d_in[6];
    const float* att   = (const float*)d_in[7];
    const float* root  = (const float*)d_in[8];
    const float* convb = (const float*)d_in[9];
    const float* wih   = (const float*)d_in[10];
    const float* whh   = (const float*)d_in[11];
    const float* bih   = (const float*)d_in[12];
    const float* bhh   = (const float*)d_in[13];
    const float* l1w   = (const float*)d_in[14];
    const float* l1b   = (const float*)d_in[15];
    const float* l2w   = (const float*)d_in[16];
    const float* l2b   = (const float*)d_in[17];
    const int* src = ei;
    const int* dst = ei + NE;
    float* out = (float*)d_out;

    char* ws = (char*)d_ws;
    size_t off = 0;
    auto alloc = [&](size_t bytes) {
        void* p = ws + off;
        off = (off + bytes + 255) & ~(size_t)255;
        return p;
    };
    float* W5    = (float*)alloc((size_t)NR * DD * DD * 4);
    float* h     = (float*)alloc((size_t)NN * DD * 4);
    float* agg   = (float*)alloc((size_t)NN * DD * 4);
    float* hrel  = (float*)alloc((size_t)NR * NN * DD * 4);
    float* cnt   = (float*)alloc((size_t)NN * 4);
    float* esc   = (float*)alloc((size_t)NN * 4);
    int*   seg   = (int*)alloc((size_t)(NG + 1) * 4);
    float* qstar = (float*)alloc((size_t)NG * 2 * DD * 4);
    float* hx    = (float*)alloc((size_t)NG * DD * 4);
    float* cx    = (float*)alloc((size_t)NG * DD * 4);

    hipMemsetAsync(cnt, 0, (size_t)NN * 4, stream);
    hipMemsetAsync(qstar, 0, (size_t)NG * 2 * DD * 4, stream);
    hipMemsetAsync(hx, 0, (size_t)NG * DD * 4, stream);
    hipMemsetAsync(cx, 0, (size_t)NG * DD * 4, stream);

    k_w<<<(NR * DD * DD + 255) / 256, 256, 0, stream>>>(att, basis, W5);
    k_cnt<<<(NE + 255) / 256, 256, 0, stream>>>(dst, cnt);
    k_inv<<<(NN + 255) / 256, 256, 0, stream>>>(cnt);
    k_seg<<<(NG + 256) / 256, 256, 0, stream>>>(batch, seg);
    k_lin0<<<(NN + 255) / 256, 256, 0, stream>>>(x, l0w, l0b, h);

    for (int s = 0; s < 6; ++s) {
        k_transform<<<dim3((NN + 255) / 256, 6), 256, 0, stream>>>(h, W5, root, hrel, agg);
        k_scatter<<<NE / 4, 256, 0, stream>>>(hrel, src, dst, etype, cnt, agg);
        k_relub<<<(NN * DD / 4 + 255) / 256, 256, 0, stream>>>(agg, convb, h);
    }

    for (int t = 0; t < 6; ++t) {
        k_lstm<<<NG, 64, 0, stream>>>(qstar, hx, cx, wih, whh, bih, bhh);
        k_attn<<<NG, 256, 0, stream>>>(h, seg, hx, qstar, esc);
    }

    k_final<<<NG, 64, 0, stream>>>(qstar, l1w, l1b, l2w, l2b, out);
}